// Round 7
// baseline (728.833 us; speedup 1.0000x reference)
//
#include <hip/hip_runtime.h>
#include <hip/hip_cooperative_groups.h>
#include <math.h>

namespace cg = cooperative_groups;

#define BB 16
#define CC 256
#define HH 128
#define WW 128
#define HWP (HH * WW)               // 16384 pixels per (b,c) plane
#define P4  (HWP / 4)               // 4096 float4 per plane
#define PLANE ((size_t)CC * HWP)

typedef float f4 __attribute__((ext_vector_type(4)));

// ===========================================================================
// Path 1: fused cooperative kernel.  1024 blocks x 256 threads, 4 blocks/CU
// (gated host-side by an occupancy query; coop launch also validates).
//   A: thread->(b,q,p4) reduces 64 channels ascending -> psum/pmax[q][b][hw]
//   B: thread->(b,hw) combines quarters + 3x3 zero-pad conv + hardsigmoid
//   C: same (b,q,p4) map, channels DESCENDING (A's tail = C's head for L3
//      recency).  Normal loads for x (hit-if-present), nt-stores for out
//      (don't evict x from Infinity Cache).
// ===========================================================================
__global__ __launch_bounds__(256, 4) void fused_kernel(
    const float* __restrict__ x,
    const float* __restrict__ cw,     // [1][2][3][3]: [0..8]=avg-ch, [9..17]=max-ch
    float* __restrict__ psum,         // [4][B][HW]
    float* __restrict__ pmax,         // [4][B][HW]
    float* __restrict__ amap,         // [B][HW]
    float* __restrict__ out)
{
    cg::grid_group grid = cg::this_grid();

    int t  = blockIdx.x * 256 + threadIdx.x;   // 0 .. 262143
    int p4 = t & (P4 - 1);
    int q  = (t >> 12) & 3;                    // channel quarter (64 ch)
    int b  = t >> 14;

    // ---------------- Phase A: partial channel reduce ----------------
    {
        const f4* xp = (const f4*)(x + (size_t)b * PLANE + (size_t)q * 64 * HWP) + p4;
        f4 s = {0.f, 0.f, 0.f, 0.f};
        f4 m = {-INFINITY, -INFINITY, -INFINITY, -INFINITY};
        #pragma unroll 8
        for (int c = 0; c < 64; ++c) {          // ascending
            f4 v = xp[(size_t)c * P4];
            s.x += v.x; s.y += v.y; s.z += v.z; s.w += v.w;
            m.x = fmaxf(m.x, v.x); m.y = fmaxf(m.y, v.y);
            m.z = fmaxf(m.z, v.z); m.w = fmaxf(m.w, v.w);
        }
        ((f4*)(psum + ((size_t)q * BB + b) * HWP))[p4] = s;
        ((f4*)(pmax + ((size_t)q * BB + b) * HWP))[p4] = m;
    }

    grid.sync();

    // ---------------- Phase B: conv + hardsigmoid -> amap ----------------
    {
        int hw = t & (HWP - 1);
        int bc = t >> 14;
        int h  = hw >> 7;
        int w  = hw & (WW - 1);

        float wa[9], wm[9];
        #pragma unroll
        for (int i = 0; i < 9; ++i) { wa[i] = cw[i]; wm[i] = cw[9 + i]; }

        const float* s0 = psum + (size_t)bc * HWP;
        const float* m0 = pmax + (size_t)bc * HWP;
        const size_t qs = (size_t)BB * HWP;

        float acc = 0.f;
        #pragma unroll
        for (int ki = 0; ki < 3; ++ki) {
            int hh = h + ki - 1;
            if (hh < 0 || hh >= HH) continue;
            #pragma unroll
            for (int kj = 0; kj < 3; ++kj) {
                int ww = w + kj - 1;
                if (ww < 0 || ww >= WW) continue;
                int n = hh * WW + ww;
                float sv = s0[n] + s0[n + qs] + s0[n + 2 * qs] + s0[n + 3 * qs];
                float mv = fmaxf(fmaxf(m0[n], m0[n + qs]),
                                 fmaxf(m0[n + 2 * qs], m0[n + 3 * qs]));
                acc += wa[ki * 3 + kj] * (sv * (1.f / 256.f)) + wm[ki * 3 + kj] * mv;
            }
        }
        amap[t] = fminf(fmaxf(acc + 3.f, 0.f), 6.f) * (1.f / 6.f);
    }

    grid.sync();

    // ---------------- Phase C: out = x * a ----------------
    {
        f4 a = *((const f4*)(amap + (size_t)b * HWP) + p4);

        const f4* xp = (const f4*)(x   + (size_t)b * PLANE + (size_t)q * 64 * HWP) + p4;
        f4*       op = (f4*)      (out + (size_t)b * PLANE + (size_t)q * 64 * HWP) + p4;

        #pragma unroll 8
        for (int ci = 63; ci >= 0; --ci) {      // descending: freshest-in-L3 first
            f4 v = xp[(size_t)ci * P4];
            f4 r;
            r.x = v.x * a.x; r.y = v.y * a.y; r.z = v.z * a.z; r.w = v.w * a.w;
            __builtin_nontemporal_store(r, op + (size_t)ci * P4);
        }
    }
}

// ===========================================================================
// Path 2 (fallback): verified R3 three-kernel pipeline.
// ===========================================================================
__global__ __launch_bounds__(256) void reduce_kernel(
    const float* __restrict__ x,
    float* __restrict__ psum,       // [2][B][HW]
    float* __restrict__ pmax)
{
    int t    = blockIdx.x * 256 + threadIdx.x;
    int p4   = t & (P4 - 1);
    int half = (t >> 12) & 1;
    int b    = t >> 13;

    const f4* xp = (const f4*)(x + (size_t)b * PLANE + (size_t)half * 128 * HWP) + p4;

    f4 s = {0.f, 0.f, 0.f, 0.f};
    f4 m = {-INFINITY, -INFINITY, -INFINITY, -INFINITY};
    #pragma unroll 8
    for (int c = 0; c < 128; ++c) {
        f4 v = xp[(size_t)c * P4];
        s.x += v.x; s.y += v.y; s.z += v.z; s.w += v.w;
        m.x = fmaxf(m.x, v.x); m.y = fmaxf(m.y, v.y);
        m.z = fmaxf(m.z, v.z); m.w = fmaxf(m.w, v.w);
    }

    ((f4*)(psum + ((size_t)half * BB + b) * HWP))[p4] = s;
    ((f4*)(pmax + ((size_t)half * BB + b) * HWP))[p4] = m;
}

__global__ __launch_bounds__(256) void conv_kernel(
    const float* __restrict__ cw,
    const float* __restrict__ psum,
    const float* __restrict__ pmax,
    float* __restrict__ amap)
{
    int t  = blockIdx.x * 256 + threadIdx.x;
    int hw = t & (HWP - 1);
    int b  = t >> 14;
    int h  = hw >> 7;
    int w  = hw & (WW - 1);

    float wa[9], wm[9];
    #pragma unroll
    for (int i = 0; i < 9; ++i) { wa[i] = cw[i]; wm[i] = cw[9 + i]; }

    const float* s0 = psum + (size_t)b * HWP;
    const float* s1 = psum + ((size_t)BB + b) * HWP;
    const float* m0 = pmax + (size_t)b * HWP;
    const float* m1 = pmax + ((size_t)BB + b) * HWP;

    float acc = 0.f;
    #pragma unroll
    for (int ki = 0; ki < 3; ++ki) {
        int hh = h + ki - 1;
        if (hh < 0 || hh >= HH) continue;
        #pragma unroll
        for (int kj = 0; kj < 3; ++kj) {
            int ww = w + kj - 1;
            if (ww < 0 || ww >= WW) continue;
            int n = hh * WW + ww;
            float avg = (s0[n] + s1[n]) * (1.f / 256.f);
            float mx  = fmaxf(m0[n], m1[n]);
            acc += wa[ki * 3 + kj] * avg + wm[ki * 3 + kj] * mx;
        }
    }
    amap[t] = fminf(fmaxf(acc + 3.f, 0.f), 6.f) * (1.f / 6.f);
}

__global__ __launch_bounds__(256) void apply_kernel(
    const float* __restrict__ x,
    const float* __restrict__ amap,
    float* __restrict__ out)
{
    int t  = blockIdx.x * 256 + threadIdx.x;
    int p4 = t & (P4 - 1);
    int g  = (t >> 12) & 3;
    int b  = t >> 14;

    f4 a = *((const f4*)(amap + (size_t)b * HWP) + p4);

    const f4* xp = (const f4*)(x   + (size_t)b * PLANE + (size_t)g * 64 * HWP) + p4;
    f4*       op = (f4*)      (out + (size_t)b * PLANE + (size_t)g * 64 * HWP) + p4;

    #pragma unroll 8
    for (int ci = 63; ci >= 0; --ci) {
        f4 v = xp[(size_t)ci * P4];
        f4 r;
        r.x = v.x * a.x; r.y = v.y * a.y; r.z = v.z * a.z; r.w = v.w * a.w;
        __builtin_nontemporal_store(r, op + (size_t)ci * P4);
    }
}

extern "C" void kernel_launch(void* const* d_in, const int* in_sizes, int n_in,
                              void* d_out, int out_size, void* d_ws, size_t ws_size,
                              hipStream_t stream)
{
    const float* x  = (const float*)d_in[0];
    const float* cw = (const float*)d_in[1];
    float* out      = (float*)d_out;

    float* psum = (float*)d_ws;                          // up to 4 MB
    float* pmax = psum + (size_t)4 * BB * HWP;           // up to 4 MB
    float* amap = pmax + (size_t)4 * BB * HWP;           // 1 MB

    // Deterministic, capture-safe host query: coop path only if the full
    // 1024-block grid is guaranteed co-resident (>= 4 blocks/CU, 256 CUs).
    int maxb = 0;
    hipError_t qerr = hipOccupancyMaxActiveBlocksPerMultiprocessor(
        &maxb, fused_kernel, 256, 0);

    if (qerr == hipSuccess && maxb >= 4) {
        void* args[] = { (void*)&x, (void*)&cw, (void*)&psum,
                         (void*)&pmax, (void*)&amap, (void*)&out };
        hipError_t lerr = hipLaunchCooperativeKernel(
            (const void*)fused_kernel, dim3(1024), dim3(256), args, 0, stream);
        if (lerr == hipSuccess) return;
    }

    // Fallback: verified three-kernel pipeline (R3 structure).
    reduce_kernel<<<512,  256, 0, stream>>>(x, psum, pmax);
    conv_kernel  <<<1024, 256, 0, stream>>>(cw, psum, pmax, amap);
    apply_kernel <<<1024, 256, 0, stream>>>(x, amap, out);
}